// Round 5
// baseline (1572.648 us; speedup 1.0000x reference)
//
#include <hip/hip_runtime.h>
#include <hip/hip_bf16.h>
#include <math.h>

#define BB 4
#define TT 4096
#define DD 1024
#define HH 16
#define DFF 4096
#define KSEL 2048

typedef __attribute__((ext_vector_type(8))) short short8;
typedef __attribute__((ext_vector_type(4))) float f32x4;

__device__ __forceinline__ unsigned short f2bf(float f) {
  union { float f; unsigned int i; } v; v.f = f;
  unsigned int x = v.i;
  unsigned int r = (x + 0x7fffu + ((x >> 16) & 1u)) >> 16;
  return (unsigned short)r;
}
__device__ __forceinline__ float bf2f(unsigned short u) {
  union { unsigned int i; float f; } v; v.i = ((unsigned int)u) << 16; return v.f;
}

// ---------------- f32 -> bf16 conversion (weights) ----------------
__global__ void cvt_kernel(const float* __restrict__ src, unsigned short* __restrict__ dst, int n) {
  int i = (blockIdx.x * 256 + threadIdx.x) * 4;
  if (i + 3 < n) {
    float4 v = *(const float4*)(src + i);
    ushort4 o;
    o.x = f2bf(v.x); o.y = f2bf(v.y); o.z = f2bf(v.z); o.w = f2bf(v.w);
    *(ushort4*)(dst + i) = o;
  }
}

// ---------------- router: f64 dot per token + sigmoid ----------------
__global__ void router_kernel(const float* __restrict__ x,
                              const float* __restrict__ wr,
                              double* __restrict__ dots, float* __restrict__ sig) {
  int token = blockIdx.x * 4 + (threadIdx.x >> 6);
  int lane = threadIdx.x & 63;
  const float* xr = x + (size_t)token * DD;
  double s = 0.0;
  for (int j = lane; j < DD; j += 64)
    s += (double)xr[j] * (double)wr[j];
  for (int o = 32; o > 0; o >>= 1) s += __shfl_down(s, o);
  if (lane == 0) {
    dots[token] = s;
    sig[token] = 1.0f / (1.0f + expf((float)(-s)));
  }
}

// ---------------- rank: count tokens strictly ahead; flag top-k ----------------
__global__ void rank_kernel(const double* __restrict__ dots, int* __restrict__ flags) {
  __shared__ double sd[TT];
  int b = blockIdx.x >> 4;
  int chunk = blockIdx.x & 15;
  const double* drow = dots + (size_t)b * TT;
  for (int j = threadIdx.x; j < TT; j += 256) sd[j] = drow[j];
  __syncthreads();
  int i = chunk * 256 + threadIdx.x;
  double di = sd[i];
  int cnt = 0;
  for (int j = 0; j < TT; ++j) {
    double dj = sd[j];
    cnt += (int)((dj > di) || (dj == di && j < i));
  }
  flags[(size_t)b * TT + i] = (cnt < KSEL) ? 1 : 0;
}

// ---------------- compact: ascending selected indices + batch score mean ----------------
__global__ void compact_kernel(const int* __restrict__ flags, const float* __restrict__ sig,
                               int* __restrict__ idx, float* __restrict__ means) {
  __shared__ int part[256];
  __shared__ float ssum[256];
  int b = blockIdx.x;
  const int* f = flags + (size_t)b * TT;
  int tid = threadIdx.x;
  int local = 0; float fs = 0.f;
  for (int j = 0; j < 16; ++j) {
    local += f[tid * 16 + j];
    fs += sig[(size_t)b * TT + tid * 16 + j];
  }
  part[tid] = local; ssum[tid] = fs;
  __syncthreads();
  if (tid == 0) {
    int run = 0;
    for (int t = 0; t < 256; ++t) { int c = part[t]; part[t] = run; run += c; }
    float tot = 0.f;
    for (int t = 0; t < 256; ++t) tot += ssum[t];
    means[b] = tot / (float)TT;
  }
  __syncthreads();
  int pos = part[tid];
  for (int j = 0; j < 16; ++j) {
    int t = tid * 16 + j;
    if (f[t]) { idx[(size_t)b * KSEL + pos] = t; ++pos; }
  }
}

__global__ void aux_kernel(const float* __restrict__ means, float* __restrict__ out_aux) {
  if (threadIdx.x == 0 && blockIdx.x == 0) {
    float m = 0.f;
    for (int b = 0; b < BB; ++b) m += means[b];
    m *= (1.0f / BB);
    float v = 0.f;
    for (int b = 0; b < BB; ++b) { float d = means[b] - m; v += d * d; }
    v /= (float)(BB - 1);
    *out_aux = v;
  }
}

// ---------------- layernorm: f32 src (optional gather), bf16 dst ----------------
__global__ void ln_kernel(const float* __restrict__ src,
                          const int* __restrict__ idx,
                          const float* __restrict__ scale,
                          const float* __restrict__ bias,
                          unsigned short* __restrict__ dst) {
  int r = blockIdx.x;  // 0..KSEL-1 (batch-local)
  const float* row;
  if (idx) {
    int t = idx[r];
    row = src + (size_t)t * DD;
  } else {
    row = src + (size_t)r * DD;
  }
  __shared__ float red[8];
  __shared__ float mv[2];
  int tid = threadIdx.x;
  float vals[4];
  float s = 0.f, ss = 0.f;
  for (int j = 0; j < 4; ++j) {
    float v = row[tid + 256 * j];
    vals[j] = v; s += v; ss += v * v;
  }
  for (int o = 32; o > 0; o >>= 1) { s += __shfl_down(s, o); ss += __shfl_down(ss, o); }
  int wid = tid >> 6, lane = tid & 63;
  if (lane == 0) { red[wid] = s; red[wid + 4] = ss; }
  __syncthreads();
  if (tid == 0) {
    float a = red[0] + red[1] + red[2] + red[3];
    float q = red[4] + red[5] + red[6] + red[7];
    float mean = a / (float)DD;
    float var = fmaxf(q / (float)DD - mean * mean, 0.f);
    mv[0] = mean; mv[1] = rsqrtf(var + 1e-5f);
  }
  __syncthreads();
  float mean = mv[0], rst = mv[1];
  unsigned short* drow = dst + (size_t)r * DD;
  for (int j = 0; j < 4; ++j) {
    int c = tid + 256 * j;
    float v = (vals[j] - mean) * rst * scale[c] + bias[c];
    drow[c] = f2bf(v);
  }
}

// ---------------- BT-form MFMA GEMM: acc = A[M,K](bf16) * W[N,K]^T(bf16) ----------------
// EPI 0: Cb[row*N+col] = bf16(acc)                       (qkv)
// EPI 1: fout[row*DD+col] = xin[idx[row]*DD+col] + acc   (x1 = x_sel + attn, f32)
// EPI 2: fout[idx[row]*DD+col] = xin[row*DD+col] + acc   (scatter out = x1 + ffn, f32)
template <int EPI>
__launch_bounds__(256, 2)
__global__ void gemm_bt(const unsigned short* __restrict__ A,
                        const unsigned short* __restrict__ W,
                        int K, int N,
                        unsigned short* __restrict__ Cb,
                        const int* __restrict__ idx,
                        const float* __restrict__ xin,
                        float* __restrict__ fout) {
  __shared__ unsigned short As[128][40];
  __shared__ unsigned short Bs[128][40];
  int bm = blockIdx.x, bn = blockIdx.y;
  int tid = threadIdx.x;
  int wid = tid >> 6, lane = tid & 63;
  int quad = lane >> 4, l15 = lane & 15;
  int wm = (wid >> 1) * 64, wn = (wid & 1) * 64;

  f32x4 acc[4][4] = {};
  const int arow0 = bm * 128, brow0 = bn * 128;
  int srow = tid >> 2;
  int scol = (tid & 3) * 8;
  const unsigned short* Ag = A + (size_t)(arow0 + srow) * K + scol;
  const unsigned short* Wg = W + (size_t)(brow0 + srow) * K + scol;

  for (int k0 = 0; k0 < K; k0 += 32) {
    uint4 a0 = *(const uint4*)(Ag + k0);
    uint4 a1 = *(const uint4*)(Ag + (size_t)64 * K + k0);
    uint4 b0 = *(const uint4*)(Wg + k0);
    uint4 b1 = *(const uint4*)(Wg + (size_t)64 * K + k0);
    __syncthreads();
    *(uint4*)&As[srow][scol] = a0;
    *(uint4*)&As[srow + 64][scol] = a1;
    *(uint4*)&Bs[srow][scol] = b0;
    *(uint4*)&Bs[srow + 64][scol] = b1;
    __syncthreads();
    short8 af[4], bfr[4];
    for (int t = 0; t < 4; ++t) af[t] = *(const short8*)&As[wm + t * 16 + l15][quad * 8];
    for (int t = 0; t < 4; ++t) bfr[t] = *(const short8*)&Bs[wn + t * 16 + l15][quad * 8];
    for (int i = 0; i < 4; ++i)
      for (int j = 0; j < 4; ++j)
        acc[i][j] = __builtin_amdgcn_mfma_f32_16x16x32_bf16(af[i], bfr[j], acc[i][j], 0, 0, 0);
  }

  for (int i = 0; i < 4; ++i)
    for (int j = 0; j < 4; ++j)
      for (int r = 0; r < 4; ++r) {
        int row = arow0 + wm + i * 16 + quad * 4 + r;
        int col = brow0 + wn + j * 16 + l15;
        float v = acc[i][j][r];
        if (EPI == 0) {
          Cb[(size_t)row * N + col] = f2bf(v);
        } else if (EPI == 1) {
          int t = idx[row];
          fout[(size_t)row * DD + col] = xin[(size_t)t * DD + col] + v;
        } else {
          int t = idx[row];
          fout[(size_t)t * DD + col] = xin[(size_t)row * DD + col] + v;
        }
      }
}

// ---------------- dual-B GEMM for SwiGLU: g = silu(A*W1^T) * (A*W2^T), bf16 out ----------------
__launch_bounds__(256, 2)
__global__ void gemm_dual(const unsigned short* __restrict__ A,
                          const unsigned short* __restrict__ W1,
                          const unsigned short* __restrict__ W2,
                          unsigned short* __restrict__ G,
                          int K, int N) {
  __shared__ unsigned short As[128][40];
  __shared__ unsigned short B1s[128][40];
  __shared__ unsigned short B2s[128][40];
  int bm = blockIdx.x, bn = blockIdx.y;
  int tid = threadIdx.x;
  int wid = tid >> 6, lane = tid & 63;
  int quad = lane >> 4, l15 = lane & 15;
  int wm = (wid >> 1) * 64, wn = (wid & 1) * 64;

  f32x4 acc1[4][4] = {};
  f32x4 acc2[4][4] = {};
  const int arow0 = bm * 128, brow0 = bn * 128;
  int srow = tid >> 2;
  int scol = (tid & 3) * 8;
  const unsigned short* Ag = A + (size_t)(arow0 + srow) * K + scol;
  const unsigned short* W1g = W1 + (size_t)(brow0 + srow) * K + scol;
  const unsigned short* W2g = W2 + (size_t)(brow0 + srow) * K + scol;

  for (int k0 = 0; k0 < K; k0 += 32) {
    uint4 a0 = *(const uint4*)(Ag + k0);
    uint4 a1 = *(const uint4*)(Ag + (size_t)64 * K + k0);
    uint4 c0 = *(const uint4*)(W1g + k0);
    uint4 c1 = *(const uint4*)(W1g + (size_t)64 * K + k0);
    uint4 d0 = *(const uint4*)(W2g + k0);
    uint4 d1 = *(const uint4*)(W2g + (size_t)64 * K + k0);
    __syncthreads();
    *(uint4*)&As[srow][scol] = a0;
    *(uint4*)&As[srow + 64][scol] = a1;
    *(uint4*)&B1s[srow][scol] = c0;
    *(uint4*)&B1s[srow + 64][scol] = c1;
    *(uint4*)&B2s[srow][scol] = d0;
    *(uint4*)&B2s[srow + 64][scol] = d1;
    __syncthreads();
    short8 af[4], b1f[4], b2f[4];
    for (int t = 0; t < 4; ++t) af[t] = *(const short8*)&As[wm + t * 16 + l15][quad * 8];
    for (int t = 0; t < 4; ++t) b1f[t] = *(const short8*)&B1s[wn + t * 16 + l15][quad * 8];
    for (int t = 0; t < 4; ++t) b2f[t] = *(const short8*)&B2s[wn + t * 16 + l15][quad * 8];
    for (int i = 0; i < 4; ++i)
      for (int j = 0; j < 4; ++j) {
        acc1[i][j] = __builtin_amdgcn_mfma_f32_16x16x32_bf16(af[i], b1f[j], acc1[i][j], 0, 0, 0);
        acc2[i][j] = __builtin_amdgcn_mfma_f32_16x16x32_bf16(af[i], b2f[j], acc2[i][j], 0, 0, 0);
      }
  }

  for (int i = 0; i < 4; ++i)
    for (int j = 0; j < 4; ++j)
      for (int r = 0; r < 4; ++r) {
        int row = arow0 + wm + i * 16 + quad * 4 + r;
        int col = brow0 + wn + j * 16 + l15;
        float u1 = acc1[i][j][r];
        float u2 = acc2[i][j][r];
        float sg = u1 / (1.0f + expf(-u1));  // silu
        G[(size_t)row * N + col] = f2bf(sg * u2);
      }
}

// ---------------- flash attention over selected tokens (single batch) ----------------
__launch_bounds__(256)
__global__ void attn_kernel(const unsigned short* __restrict__ qkv,
                            unsigned short* __restrict__ obuf) {
  int qb = blockIdx.x & 31;
  int h = blockIdx.x >> 5;
  int tid = threadIdx.x, wid = tid >> 6, lane = tid & 63;
  int quad = lane >> 4, l15 = lane & 15;

  __shared__ unsigned short Ks[32][72];
  __shared__ unsigned short Vt[64][40];
  __shared__ unsigned short Ps[4][16][40];

  int qrow = qb * 64 + wid * 16 + l15;
  const unsigned short* qptr = qkv + (size_t)qrow * (3 * DD) + h * 64;
  short8 aq0 = *(const short8*)(qptr + quad * 8);
  short8 aq1 = *(const short8*)(qptr + 32 + quad * 8);

  float m_r[4], l_r[4];
  f32x4 o_acc[4] = {};
  for (int r = 0; r < 4; ++r) { m_r[r] = -1e30f; l_r[r] = 0.f; }

  int skey = tid >> 3;
  int scol = (tid & 7) * 8;
  const unsigned short* kbase = qkv + DD + h * 64;
  const unsigned short* vbase = qkv + 2 * DD + h * 64;

  for (int kt = 0; kt < KSEL / 32; ++kt) {
    int key0 = kt * 32;
    uint4 kv = *(const uint4*)(kbase + (size_t)(key0 + skey) * (3 * DD) + scol);
    uint4 vv = *(const uint4*)(vbase + (size_t)(key0 + skey) * (3 * DD) + scol);
    __syncthreads();
    *(uint4*)&Ks[skey][scol] = kv;
    const unsigned short* vp = (const unsigned short*)&vv;
    for (int j = 0; j < 8; ++j) Vt[scol + j][skey] = vp[j];
    __syncthreads();

    f32x4 s0 = {0.f, 0.f, 0.f, 0.f}, s1 = {0.f, 0.f, 0.f, 0.f};
    short8 k00 = *(const short8*)&Ks[l15][quad * 8];
    short8 k01 = *(const short8*)&Ks[l15][32 + quad * 8];
    short8 k10 = *(const short8*)&Ks[16 + l15][quad * 8];
    short8 k11 = *(const short8*)&Ks[16 + l15][32 + quad * 8];
    s0 = __builtin_amdgcn_mfma_f32_16x16x32_bf16(aq0, k00, s0, 0, 0, 0);
    s0 = __builtin_amdgcn_mfma_f32_16x16x32_bf16(aq1, k01, s0, 0, 0, 0);
    s1 = __builtin_amdgcn_mfma_f32_16x16x32_bf16(aq0, k10, s1, 0, 0, 0);
    s1 = __builtin_amdgcn_mfma_f32_16x16x32_bf16(aq1, k11, s1, 0, 0, 0);

    float p0[4], p1[4], alpha[4];
    for (int r = 0; r < 4; ++r) {
      float s0v = s0[r] * 0.125f, s1v = s1[r] * 0.125f;
      float mx = fmaxf(s0v, s1v);
      for (int o = 1; o < 16; o <<= 1) mx = fmaxf(mx, __shfl_xor(mx, o));
      float mnew = fmaxf(m_r[r], mx);
      alpha[r] = expf(m_r[r] - mnew);
      p0[r] = expf(s0v - mnew);
      p1[r] = expf(s1v - mnew);
      float ls = p0[r] + p1[r];
      for (int o = 1; o < 16; o <<= 1) ls += __shfl_xor(ls, o);
      l_r[r] = l_r[r] * alpha[r] + ls;
      m_r[r] = mnew;
    }
    for (int dt = 0; dt < 4; ++dt)
      for (int r = 0; r < 4; ++r) o_acc[dt][r] *= alpha[r];

    for (int r = 0; r < 4; ++r) {
      Ps[wid][quad * 4 + r][l15] = f2bf(p0[r]);
      Ps[wid][quad * 4 + r][16 + l15] = f2bf(p1[r]);
    }
    short8 ap = *(const short8*)&Ps[wid][l15][quad * 8];
    for (int dt = 0; dt < 4; ++dt) {
      short8 vf = *(const short8*)&Vt[dt * 16 + l15][quad * 8];
      o_acc[dt] = __builtin_amdgcn_mfma_f32_16x16x32_bf16(ap, vf, o_acc[dt], 0, 0, 0);
    }
  }

  int orow = qb * 64 + wid * 16 + quad * 4;
  unsigned short* op = obuf + h * 64;
  for (int dt = 0; dt < 4; ++dt)
    for (int r = 0; r < 4; ++r) {
      float v = o_acc[dt][r] / l_r[r];
      op[(size_t)(orow + r) * DD + dt * 16 + l15] = f2bf(v);
    }
}

// ---------------- launch: f32 I/O, per-batch pipeline, 61 MiB workspace ----------------
extern "C" void kernel_launch(void* const* d_in, const int* in_sizes, int n_in,
                              void* d_out, int out_size, void* d_ws, size_t ws_size,
                              hipStream_t stream) {
  const float* x    = (const float*)d_in[0];
  const float* wr   = (const float*)d_in[1];
  const float* ln1s = (const float*)d_in[2];
  const float* ln1b = (const float*)d_in[3];
  const float* ln2s = (const float*)d_in[4];
  const float* ln2b = (const float*)d_in[5];
  const float* wqkv = (const float*)d_in[6];
  const float* wout = (const float*)d_in[7];
  const float* w1   = (const float*)d_in[8];
  const float* w2   = (const float*)d_in[9];
  const float* w3   = (const float*)d_in[10];
  float* out = (float*)d_out;
  char* ws = (char*)d_ws;

  // control region [0, 1 MiB)
  double* dots  = (double*)(ws + 0);        // 128 KiB
  float*  sig   = (float*)(ws + 131072);    // 64 KiB
  int*    flags = (int*)(ws + 196608);      // 64 KiB
  int*    idx   = (int*)(ws + 262144);      // 32 KiB
  float*  means = (float*)(ws + 294912);    // 16 B
  // bf16 weight copies [1 MiB, 33 MiB)
  unsigned short* wqkv_h = (unsigned short*)(ws + ((size_t)1 << 20));   // 6 MiB
  unsigned short* wout_h = (unsigned short*)(ws + ((size_t)7 << 20));   // 2 MiB
  unsigned short* w1_h   = (unsigned short*)(ws + ((size_t)9 << 20));   // 8 MiB
  unsigned short* w2_h   = (unsigned short*)(ws + ((size_t)17 << 20));  // 8 MiB
  unsigned short* w3_h   = (unsigned short*)(ws + ((size_t)25 << 20));  // 8 MiB
  // per-batch buffers [33 MiB, 61 MiB)
  float*          x1_b   = (float*)(ws + ((size_t)33 << 20));           // 8 MiB f32
  unsigned short* norm_b = (unsigned short*)(ws + ((size_t)41 << 20));  // 4 MiB bf16
  unsigned short* qkv_b  = (unsigned short*)(ws + ((size_t)45 << 20));  // 12 MiB bf16
  unsigned short* obuf_b = (unsigned short*)(ws + ((size_t)57 << 20));  // 4 MiB bf16
  unsigned short* gbuf_b = (unsigned short*)(ws + ((size_t)45 << 20));  // 16 MiB, overlays qkv+obuf

  // out = x (pass-through for unselected tokens), f32, 64 MiB
  hipMemcpyAsync(out, x, (size_t)BB * TT * DD * sizeof(float),
                 hipMemcpyDeviceToDevice, stream);

  // weight conversions f32 -> bf16
  cvt_kernel<<<dim3(3 * DD * DD / 1024), dim3(256), 0, stream>>>(wqkv, wqkv_h, 3 * DD * DD);
  cvt_kernel<<<dim3(DD * DD / 1024), dim3(256), 0, stream>>>(wout, wout_h, DD * DD);
  cvt_kernel<<<dim3(DFF * DD / 1024), dim3(256), 0, stream>>>(w1, w1_h, DFF * DD);
  cvt_kernel<<<dim3(DFF * DD / 1024), dim3(256), 0, stream>>>(w2, w2_h, DFF * DD);
  cvt_kernel<<<dim3(DD * DFF / 1024), dim3(256), 0, stream>>>(w3, w3_h, DD * DFF);

  router_kernel<<<dim3(BB * TT / 4), dim3(256), 0, stream>>>(x, wr, dots, sig);
  rank_kernel<<<dim3(BB * 16), dim3(256), 0, stream>>>(dots, flags);
  compact_kernel<<<dim3(BB), dim3(256), 0, stream>>>(flags, sig, idx, means);
  aux_kernel<<<dim3(1), dim3(64), 0, stream>>>(means, out + (size_t)BB * TT * DD);

  for (int b = 0; b < BB; ++b) {
    const float* x_b = x + (size_t)b * TT * DD;
    const int* idx_b = idx + (size_t)b * KSEL;
    float* out_b = out + (size_t)b * TT * DD;

    // ln1 on gathered selected tokens -> bf16
    ln_kernel<<<dim3(KSEL), dim3(256), 0, stream>>>(x_b, idx_b, ln1s, ln1b, norm_b);

    // qkv = normed @ w_qkv^T  (2048 x 3072, K=1024) -> bf16
    gemm_bt<0><<<dim3(KSEL / 128, 3 * DD / 128), dim3(256), 0, stream>>>(
        norm_b, wqkv_h, DD, 3 * DD, qkv_b, nullptr, nullptr, nullptr);

    // attention -> bf16 obuf
    attn_kernel<<<dim3(HH * (KSEL / 64)), dim3(256), 0, stream>>>(qkv_b, obuf_b);

    // x1 = x_sel + o @ w_out^T  -> f32
    gemm_bt<1><<<dim3(KSEL / 128, DD / 128), dim3(256), 0, stream>>>(
        obuf_b, wout_h, DD, DD, nullptr, idx_b, x_b, x1_b);

    // ln2 -> bf16
    ln_kernel<<<dim3(KSEL), dim3(256), 0, stream>>>(x1_b, nullptr, ln2s, ln2b, norm_b);

    // g = silu(h@w1^T) * (h@w2^T)  (2048 x 4096, K=1024) -> bf16; overlays dead qkv+obuf
    gemm_dual<<<dim3(KSEL / 128, DFF / 128), dim3(256), 0, stream>>>(
        norm_b, w1_h, w2_h, gbuf_b, DD, DFF);

    // out[idx, :] = x1 + g @ w3^T  (K=4096) -> f32 scatter
    gemm_bt<2><<<dim3(KSEL / 128, DD / 128), dim3(256), 0, stream>>>(
        gbuf_b, w3_h, DFF, DD, nullptr, idx_b, x1_b, out_b);
  }
}